// Round 2
// baseline (2699.458 us; speedup 1.0000x reference)
//
#include <hip/hip_runtime.h>
#include <math.h>

// ---------------------------------------------------------------------------
// ConvVQVAE forward — fp32. VQ combine = VQ-VAE idiom: fl(fl(z2 + c2) - 2dot)
// (z^2 + e^2 - 2 z@e^T). Conv = im2col+OpenBLAS model: k=(ci,ky,kx) ascending
// fma chain with kc=384 panel flushes. z2/c2 = numpy pairwise. argmin =
// first-min ascending j.
//
// R8: deconv parity-quad form (compile-time tap indices, SGPR weight loads).
// R9: COB raised (8->32 convs, 8->16 deconvs). Per-channel fma chains are
// unchanged (COB only repartitions channels across threads), so numerics are
// bit-identical; this quadruples FMA-per-load and cuts channel-block input
// re-reads 4x. VGPR headroom was huge (28), latency-bound at 22% VALUBusy.
// ---------------------------------------------------------------------------

// ---- Conv 3x3 s2 p1, NCHW fp32, OpenBLAS kc=384 panel-split chains --------
template <int CIN, int COB, int ACT>
__global__ __launch_bounds__(256) void conv3x3_s2_blas(
    const float* __restrict__ in, const float* __restrict__ wgt,
    float* __restrict__ out, int COUT, int HIN, int WIN, int tilesW) {
  const int HOUT = HIN >> 1, WOUT = WIN >> 1;
  const int tid = threadIdx.x;
  const int tw = blockIdx.x % tilesW;
  const int th = blockIdx.x / tilesW;
  const int x = tw * 16 + (tid & 15);
  const int y = th * 16 + (tid >> 4);
  const int co0 = blockIdx.y * COB;
  const int n = blockIdx.z;
  if (x >= WOUT || y >= HOUT) return;

  float acc[COB], sum[COB];
#pragma unroll
  for (int c = 0; c < COB; ++c) { acc[c] = 0.f; sum[c] = 0.f; }

  const int iy0 = 2 * y - 1, ix0 = 2 * x - 1;
  for (int ci = 0; ci < CIN; ++ci) {
    const float* ip = in + (size_t)(n * CIN + ci) * HIN * WIN;
    float v[9];
#pragma unroll
    for (int ky = 0; ky < 3; ++ky) {
      const int iy = iy0 + ky;
      const bool yok = (unsigned)iy < (unsigned)HIN;
#pragma unroll
      for (int kx = 0; kx < 3; ++kx) {
        const int ix = ix0 + kx;
        v[ky * 3 + kx] =
            (yok && (unsigned)ix < (unsigned)WIN) ? ip[iy * WIN + ix] : 0.f;
      }
    }
#pragma unroll
    for (int t = 0; t < 9; ++t) {
      const int kk = ci * 9 + t;  // global K index, (ci,ky,kx) ascending
      if (CIN * 9 > 384 && (kk == 384 || kk == 768)) {
        // OpenBLAS kc-panel boundary: C += panel_sum (one rounded add)
#pragma unroll
        for (int c = 0; c < COB; ++c) { sum[c] = sum[c] + acc[c]; acc[c] = 0.f; }
      }
#pragma unroll
      for (int c = 0; c < COB; ++c) {
        const float* wp = wgt + ((size_t)(co0 + c) * CIN + ci) * 9;
        acc[c] = fmaf(v[t], wp[t], acc[c]);
      }
    }
  }
#pragma unroll
  for (int c = 0; c < COB; ++c) {
    float r = sum[c] + acc[c];  // final panel add (exact 0+S1 when K<=384)
    if (ACT == 1) r = fmaxf(r, 0.f);
    out[(((size_t)n * COUT + co0 + c) * HOUT + y) * WOUT + x] = r;
  }
}

// ------- ConvTranspose 3x3, stride 2, pad 1, output_pad 1, fp32 ------------
// Parity-quad form: thread (my,mx) computes outputs (2my..2my+1, 2mx..2mx+1).
// Same (ky asc, kx asc) per-ci tap order as the skipped-tap chain form;
// out-of-range neighbor inputs are 0 -> fma is a no-op.
template <int CIN, int COB, int ACT>
__global__ __launch_bounds__(256) void deconv3x3_s2_quad(
    const float* __restrict__ in, const float* __restrict__ wgt,
    float* __restrict__ out, int COUT, int HIN, int WIN, int tilesW) {
  const int HOUT = HIN * 2, WOUT = WIN * 2;
  const int tid = threadIdx.x;
  const int mx = (blockIdx.x % tilesW) * 16 + (tid & 15);
  const int my = (blockIdx.x / tilesW) * 16 + (tid >> 4);
  const int co0 = blockIdx.y * COB;
  const int n = blockIdx.z;
  if (mx >= WIN || my >= HIN) return;
  const bool xe = (mx + 1 < WIN);
  const bool ye = (my + 1 < HIN);

  float acc[COB][4];
#pragma unroll
  for (int c = 0; c < COB; ++c)
#pragma unroll
    for (int q = 0; q < 4; ++q) acc[c][q] = 0.f;

  const size_t plane = (size_t)HIN * WIN;
  const float* ip = in + (size_t)(n * CIN) * plane + (size_t)my * WIN + mx;
  for (int ci = 0; ci < CIN; ++ci, ip += plane) {
    const float v00 = ip[0];
    const float v01 = xe ? ip[1] : 0.f;
    const float v10 = ye ? ip[WIN] : 0.f;
    const float v11 = (xe && ye) ? ip[WIN + 1] : 0.f;
#pragma unroll
    for (int c = 0; c < COB; ++c) {
      const float* w = wgt + ((size_t)(co0 + c) * CIN + ci) * 9;  // uniform
      acc[c][0] = fmaf(v00, w[4], acc[c][0]);
      acc[c][1] = fmaf(v00, w[3], acc[c][1]);
      acc[c][1] = fmaf(v01, w[5], acc[c][1]);
      acc[c][2] = fmaf(v00, w[1], acc[c][2]);
      acc[c][2] = fmaf(v10, w[7], acc[c][2]);
      acc[c][3] = fmaf(v00, w[0], acc[c][3]);
      acc[c][3] = fmaf(v01, w[2], acc[c][3]);
      acc[c][3] = fmaf(v10, w[6], acc[c][3]);
      acc[c][3] = fmaf(v11, w[8], acc[c][3]);
    }
  }

  const int y0 = 2 * my, x0 = 2 * mx;
#pragma unroll
  for (int c = 0; c < COB; ++c) {
    float r[4];
#pragma unroll
    for (int q = 0; q < 4; ++q) {
      float v = acc[c][q];
      if (ACT == 1) v = fmaxf(v, 0.f);
      if (ACT == 2) v = 1.f / (1.f + expf(-v));
      r[q] = v;
    }
    float* op = out + (((size_t)n * COUT + co0 + c) * HOUT + y0) * WOUT + x0;
    float2 lo; lo.x = r[0]; lo.y = r[1];
    float2 hi; hi.x = r[2]; hi.y = r[3];
    *reinterpret_cast<float2*>(op) = lo;
    *reinterpret_cast<float2*>(op + WOUT) = hi;
  }
}

// --------- numpy scalar pairwise row-sum of squares, n=256, fp32 -----------
__global__ __launch_bounds__(256) void z2_np_k(const float* __restrict__ z,
                                               float* __restrict__ z2) {
#pragma clang fp contract(off)
  const int p = blockIdx.x * 256 + threadIdx.x;  // 32768
  const int n = p >> 10, hw = p & 1023;
  const float* zb = z + (size_t)n * 262144 + hw;
  float blk[2];
#pragma unroll
  for (int b = 0; b < 2; ++b) {
    float r[8];
#pragma unroll
    for (int j = 0; j < 8; ++j) {
      const float v = zb[(size_t)(b * 128 + j) * 1024];
      r[j] = v * v;
    }
    for (int i = 8; i < 128; i += 8) {
#pragma unroll
      for (int j = 0; j < 8; ++j) {
        const float v = zb[(size_t)(b * 128 + i + j) * 1024];
        const float m = v * v;
        r[j] = r[j] + m;
      }
    }
    blk[b] = ((r[0] + r[1]) + (r[2] + r[3])) + ((r[4] + r[5]) + (r[6] + r[7]));
  }
  z2[p] = blk[0] + blk[1];
}

__global__ __launch_bounds__(256) void c2_np_k(const float* __restrict__ cb,
                                               float* __restrict__ c2) {
#pragma clang fp contract(off)
  const int jrow = blockIdx.x * 256 + threadIdx.x;  // 1024
  const float* row = cb + (size_t)jrow * 256;
  float blk[2];
#pragma unroll
  for (int b = 0; b < 2; ++b) {
    float r[8];
#pragma unroll
    for (int j = 0; j < 8; ++j) {
      const float v = row[b * 128 + j];
      r[j] = v * v;
    }
    for (int i = 8; i < 128; i += 8) {
#pragma unroll
      for (int j = 0; j < 8; ++j) {
        const float v = row[b * 128 + i + j];
        const float m = v * v;
        r[j] = r[j] + m;
      }
    }
    blk[b] = ((r[0] + r[1]) + (r[2] + r[3])) + ((r[4] + r[5]) + (r[6] + r[7]));
  }
  c2[jrow] = blk[0] + blk[1];
}

// ------ VQ scores: dist = fl(fl(z2 + c2) - 2*dot), chain dot, first-min ----
__global__ __launch_bounds__(256) void vq_scores_f32_k(
    const float* __restrict__ z, const float* __restrict__ cb,
    const float* __restrict__ z2, const float* __restrict__ c2,
    int* __restrict__ bestid) {
  __shared__ float zS[32][64];  // [dim-in-chunk][pixel]
  __shared__ float cS[64][33];  // [cw][dim-in-chunk]+pad
  const int tid = threadIdx.x;
  const int p0 = blockIdx.x * 64;  // 512 blocks
  const int n = p0 >> 10;
  const int hw0 = p0 & 1023;
  const float* zb = z + (size_t)n * 262144 + hw0;

  const int tp = tid >> 4;  // 0..15 : pixel group (4 pixels)
  const int tj = tid & 15;  // 0..15 : codeword lane

  float z2v[4];
#pragma unroll
  for (int ii = 0; ii < 4; ++ii) z2v[ii] = z2[p0 + tp * 4 + ii];

  float run_d[4];
  int run_id[4];
#pragma unroll
  for (int ii = 0; ii < 4; ++ii) { run_d[ii] = 3.4e38f; run_id[ii] = 0; }

  for (int j0 = 0; j0 < 1024; j0 += 64) {
    float acc[4][4];
#pragma unroll
    for (int a = 0; a < 4; ++a)
#pragma unroll
      for (int b = 0; b < 4; ++b) acc[a][b] = 0.f;

    for (int k0 = 0; k0 < 256; k0 += 32) {
      __syncthreads();
#pragma unroll
      for (int i = 0; i < 8; ++i) {
        const int q = i * 256 + tid;         // 0..2047
        const int zc = q >> 6, zl = q & 63;  // dim-in-chunk, pixel
        zS[zc][zl] = zb[(size_t)(k0 + zc) * 1024 + zl];
        const int cj = q >> 5, cd = q & 31;  // codeword, dim-in-chunk
        cS[cj][cd] = cb[(size_t)(j0 + cj) * 256 + k0 + cd];
      }
      __syncthreads();
#pragma unroll
      for (int d = 0; d < 32; ++d) {
        const float za = zS[d][tp * 4 + 0];
        const float zbv = zS[d][tp * 4 + 1];
        const float zc = zS[d][tp * 4 + 2];
        const float zd = zS[d][tp * 4 + 3];
        const float c0 = cS[0 * 16 + tj][d];
        const float c1 = cS[1 * 16 + tj][d];
        const float c2v = cS[2 * 16 + tj][d];
        const float c3 = cS[3 * 16 + tj][d];
        acc[0][0] = fmaf(za, c0, acc[0][0]);
        acc[0][1] = fmaf(za, c1, acc[0][1]);
        acc[0][2] = fmaf(za, c2v, acc[0][2]);
        acc[0][3] = fmaf(za, c3, acc[0][3]);
        acc[1][0] = fmaf(zbv, c0, acc[1][0]);
        acc[1][1] = fmaf(zbv, c1, acc[1][1]);
        acc[1][2] = fmaf(zbv, c2v, acc[1][2]);
        acc[1][3] = fmaf(zbv, c3, acc[1][3]);
        acc[2][0] = fmaf(zc, c0, acc[2][0]);
        acc[2][1] = fmaf(zc, c1, acc[2][1]);
        acc[2][2] = fmaf(zc, c2v, acc[2][2]);
        acc[2][3] = fmaf(zc, c3, acc[2][3]);
        acc[3][0] = fmaf(zd, c0, acc[3][0]);
        acc[3][1] = fmaf(zd, c1, acc[3][1]);
        acc[3][2] = fmaf(zd, c2v, acc[3][2]);
        acc[3][3] = fmaf(zd, c3, acc[3][3]);
      }
    }

    {
#pragma clang fp contract(off)
#pragma unroll
      for (int ii = 0; ii < 4; ++ii) {
#pragma unroll
        for (int jj = 0; jj < 4; ++jj) {
          const int j = j0 + jj * 16 + tj;
          const float m2 = 2.0f * acc[ii][jj];  // exact (power of 2)
          const float t1 = z2v[ii] + c2[j];     // fl(A + C)   <-- VQ-VAE idiom
          const float dist = t1 - m2;           // fl(T1 - B)
          if (dist < run_d[ii] || (dist == run_d[ii] && j < run_id[ii])) {
            run_d[ii] = dist;
            run_id[ii] = j;
          }
        }
      }
    }
  }

#pragma unroll
  for (int m = 1; m < 16; m <<= 1) {
#pragma unroll
    for (int ii = 0; ii < 4; ++ii) {
      const float od = __shfl_xor(run_d[ii], m, 64);
      const int oid = __shfl_xor(run_id[ii], m, 64);
      if (od < run_d[ii] || (od == run_d[ii] && oid < run_id[ii])) {
        run_d[ii] = od;
        run_id[ii] = oid;
      }
    }
  }
  if (tj == 0) {
#pragma unroll
    for (int ii = 0; ii < 4; ++ii) bestid[p0 + tp * 4 + ii] = run_id[ii];
  }
}

// ids / e_k from bestid (exact fp32 gather)
__global__ __launch_bounds__(256) void vq_gather_k(
    const int* __restrict__ bestid, const float* __restrict__ cb,
    float* __restrict__ ek, float* __restrict__ ids) {
  const int p = blockIdx.x * 256 + threadIdx.x;  // 32768
  const int id = bestid[p];
  ids[p] = (float)id;
  const int n = p >> 10, hw = p & 1023;
  float* ekb = ek + (size_t)n * 262144 + hw;
  const float* cbr = cb + (size_t)id * 256;
  for (int c = 0; c < 256; ++c) ekb[(size_t)c * 1024] = cbr[c];
}

// ---------------------------------------------------------------------------
extern "C" void kernel_launch(void* const* d_in, const int* in_sizes, int n_in,
                              void* d_out, int out_size, void* d_ws,
                              size_t ws_size, hipStream_t stream) {
  const float* x = (const float*)d_in[0];
  const float* enc_w0 = (const float*)d_in[1];
  const float* enc_w1 = (const float*)d_in[2];
  const float* enc_w2 = (const float*)d_in[3];
  const float* codebook = (const float*)d_in[4];
  const float* dec_w0 = (const float*)d_in[5];
  const float* dec_w1 = (const float*)d_in[6];
  const float* dec_w2 = (const float*)d_in[7];

  float* out = (float*)d_out;          // 6,291,456
  float* z_out = out + 6291456;        // 8,388,608
  float* ek_out = z_out + 8388608;     // 8,388,608
  float* ids_out = ek_out + 8388608;   // 32,768

  float* ws = (float*)d_ws;
  float* h1 = ws;                      // 33,554,432 f  (32,64,128,128)
  float* h2 = ws + 33554432;           // 16,777,216 f  (32,128,64,64)
  float* d1 = h2;                      // alias (h2 dead after conv3)
  float* d2 = h1;                      // alias (h1 dead after conv2)
  float* s = ws + 50331648;
  float* z2 = s;                       // 32,768 f
  float* c2 = s + 32768;               //  1,024 f
  int* bestid = (int*)(s + 33792);     // 32,768 i32

  // ---- encoder (fp32, im2col chain + kc=384 panel splits) ----
  conv3x3_s2_blas<3, 32, 1><<<dim3(64, 2, 32), 256, 0, stream>>>(
      x, enc_w0, h1, 64, 256, 256, 8);
  conv3x3_s2_blas<64, 32, 1><<<dim3(16, 4, 32), 256, 0, stream>>>(
      h1, enc_w1, h2, 128, 128, 128, 4);
  conv3x3_s2_blas<128, 32, 0><<<dim3(4, 8, 32), 256, 0, stream>>>(
      h2, enc_w2, z_out, 256, 64, 64, 2);

  // ---- VQ (fp32; dist = (z2 + c2) - 2dot) ----
  z2_np_k<<<128, 256, 0, stream>>>(z_out, z2);
  c2_np_k<<<4, 256, 0, stream>>>(codebook, c2);
  vq_scores_f32_k<<<512, 256, 0, stream>>>(z_out, codebook, z2, c2, bestid);
  vq_gather_k<<<128, 256, 0, stream>>>(bestid, codebook, ek_out, ids_out);

  // ---- decoder (fp32, parity-quad deconv) ----
  deconv3x3_s2_quad<256, 16, 1><<<dim3(4, 8, 32), 256, 0, stream>>>(
      ek_out, dec_w0, d1, 128, 32, 32, 2);
  deconv3x3_s2_quad<128, 16, 1><<<dim3(16, 4, 32), 256, 0, stream>>>(
      d1, dec_w1, d2, 64, 64, 64, 4);
  deconv3x3_s2_quad<64, 3, 2><<<dim3(64, 1, 32), 256, 0, stream>>>(
      d2, dec_w2, out, 3, 128, 128, 8);
}

// Round 3
// 2046.922 us; speedup vs baseline: 1.3188x; 1.3188x over previous
//
#include <hip/hip_runtime.h>
#include <math.h>

// ---------------------------------------------------------------------------
// ConvVQVAE forward — fp32. VQ combine = VQ-VAE idiom: fl(fl(z2 + c2) - 2dot)
// (z^2 + e^2 - 2 z@e^T). Conv = im2col+OpenBLAS model: k=(ci,ky,kx) ascending
// fma chain with kc=384 panel flushes. z2/c2 = numpy pairwise. argmin =
// first-min ascending j.
//
// R8: deconv parity-quad form (compile-time tap indices, SGPR weight loads).
// R9 lesson: COB↑ keeps FMA:weight-scalar at 1:1 and just kills TLP — wrong
// lever. R10: PIXEL blocking. conv: PY=4 output rows/thread (288 fma : 72
// weight scalars : 27 loads per ci). deconv: QX=2 adjacent cells/thread
// (share all weights, float4 stores). Per-output fma chains are bit-identical
// (PY/QX only repartition outputs across threads; kc-flush fires at the same
// chain position).
// ---------------------------------------------------------------------------

// ---- Conv 3x3 s2 p1, NCHW fp32, PY output rows per thread -----------------
template <int CIN, int COB, int PY, int LX, int ACT>
__global__ __launch_bounds__(256) void conv3x3_s2_py(
    const float* __restrict__ in, const float* __restrict__ wgt,
    float* __restrict__ out, int COUT, int HIN, int WIN, int tilesW) {
  const int HOUT = HIN >> 1, WOUT = WIN >> 1;
  const int YG = 256 / LX;  // y-groups per block
  const int tid = threadIdx.x;
  const int x = (blockIdx.x % tilesW) * LX + (tid % LX);
  const int y0 = (blockIdx.x / tilesW) * (YG * PY) + (tid / LX) * PY;
  const int co0 = blockIdx.y * COB;
  const int n = blockIdx.z;
  if (x >= WOUT || y0 >= HOUT) return;

  float acc[COB][PY], sum[COB][PY];
#pragma unroll
  for (int c = 0; c < COB; ++c)
#pragma unroll
    for (int r = 0; r < PY; ++r) { acc[c][r] = 0.f; sum[c][r] = 0.f; }

  const int ix0 = 2 * x - 1;
  const int iy0 = 2 * y0 - 1;  // row j in [0, 2*PY+1): iy = iy0 + j
  for (int ci = 0; ci < CIN; ++ci) {
    const float* ip = in + (size_t)(n * CIN + ci) * HIN * WIN;
    float v[2 * PY + 1][3];
#pragma unroll
    for (int j = 0; j < 2 * PY + 1; ++j) {
      const int iy = iy0 + j;
      const bool yok = (unsigned)iy < (unsigned)HIN;
#pragma unroll
      for (int kx = 0; kx < 3; ++kx) {
        const int ix = ix0 + kx;
        v[j][kx] =
            (yok && (unsigned)ix < (unsigned)WIN) ? ip[iy * WIN + ix] : 0.f;
      }
    }
#pragma unroll
    for (int t = 0; t < 9; ++t) {
      const int kk = ci * 9 + t;  // global K index, (ci,ky,kx) ascending
      if (CIN * 9 > 384 && (kk == 384 || kk == 768)) {
        // OpenBLAS kc-panel boundary: C += panel_sum (one rounded add)
#pragma unroll
        for (int c = 0; c < COB; ++c)
#pragma unroll
          for (int r = 0; r < PY; ++r) {
            sum[c][r] = sum[c][r] + acc[c][r];
            acc[c][r] = 0.f;
          }
      }
      const int ky = t / 3, kx = t % 3;
#pragma unroll
      for (int c = 0; c < COB; ++c) {
        const float w = wgt[((size_t)(co0 + c) * CIN + ci) * 9 + t];
#pragma unroll
        for (int r = 0; r < PY; ++r)
          acc[c][r] = fmaf(v[2 * r + ky][kx], w, acc[c][r]);
      }
    }
  }
#pragma unroll
  for (int c = 0; c < COB; ++c)
#pragma unroll
    for (int r = 0; r < PY; ++r) {
      if (y0 + r < HOUT) {
        float rv = sum[c][r] + acc[c][r];  // final panel add
        if (ACT == 1) rv = fmaxf(rv, 0.f);
        out[(((size_t)n * COUT + co0 + c) * HOUT + y0 + r) * WOUT + x] = rv;
      }
    }
}

// ------- ConvTranspose 3x3, stride 2, pad 1, output_pad 1, fp32 ------------
// Parity-quad form, QX=2: thread owns input cells (my,mx0),(my,mx0+1) ->
// outputs (2my..2my+1, 2mx0..2mx0+3). Weights shared between the two quads;
// per-output tap order (ky asc, kx asc) per ci unchanged. float4 stores.
template <int CIN, int COB, int ACT>
__global__ __launch_bounds__(256) void deconv3x3_s2_quad2(
    const float* __restrict__ in, const float* __restrict__ wgt,
    float* __restrict__ out, int COUT, int HIN, int WIN, int tilesW) {
  const int HOUT = HIN * 2, WOUT = WIN * 2;
  const int tid = threadIdx.x;
  const int mx0 = ((blockIdx.x % tilesW) * 16 + (tid & 15)) * 2;
  const int my = (blockIdx.x / tilesW) * 16 + (tid >> 4);
  const int co0 = blockIdx.y * COB;
  const int n = blockIdx.z;
  if (mx0 >= WIN || my >= HIN) return;
  const bool xe = (mx0 + 2 < WIN);  // mx0+1 always < WIN (WIN even)
  const bool ye = (my + 1 < HIN);

  float accA[COB][4], accB[COB][4];
#pragma unroll
  for (int c = 0; c < COB; ++c)
#pragma unroll
    for (int q = 0; q < 4; ++q) { accA[c][q] = 0.f; accB[c][q] = 0.f; }

  const size_t plane = (size_t)HIN * WIN;
  const float* ip = in + (size_t)(n * CIN) * plane + (size_t)my * WIN + mx0;
  for (int ci = 0; ci < CIN; ++ci, ip += plane) {
    const float v00 = ip[0];
    const float v01 = ip[1];
    const float v02 = xe ? ip[2] : 0.f;
    const float v10 = ye ? ip[WIN] : 0.f;
    const float v11 = ye ? ip[WIN + 1] : 0.f;
    const float v12 = (xe && ye) ? ip[WIN + 2] : 0.f;
#pragma unroll
    for (int c = 0; c < COB; ++c) {
      const float* w = wgt + ((size_t)(co0 + c) * CIN + ci) * 9;  // uniform
      accA[c][0] = fmaf(v00, w[4], accA[c][0]);
      accA[c][1] = fmaf(v00, w[3], accA[c][1]);
      accA[c][1] = fmaf(v01, w[5], accA[c][1]);
      accA[c][2] = fmaf(v00, w[1], accA[c][2]);
      accA[c][2] = fmaf(v10, w[7], accA[c][2]);
      accA[c][3] = fmaf(v00, w[0], accA[c][3]);
      accA[c][3] = fmaf(v01, w[2], accA[c][3]);
      accA[c][3] = fmaf(v10, w[6], accA[c][3]);
      accA[c][3] = fmaf(v11, w[8], accA[c][3]);
      accB[c][0] = fmaf(v01, w[4], accB[c][0]);
      accB[c][1] = fmaf(v01, w[3], accB[c][1]);
      accB[c][1] = fmaf(v02, w[5], accB[c][1]);
      accB[c][2] = fmaf(v01, w[1], accB[c][2]);
      accB[c][2] = fmaf(v11, w[7], accB[c][2]);
      accB[c][3] = fmaf(v01, w[0], accB[c][3]);
      accB[c][3] = fmaf(v02, w[2], accB[c][3]);
      accB[c][3] = fmaf(v11, w[6], accB[c][3]);
      accB[c][3] = fmaf(v12, w[8], accB[c][3]);
    }
  }

  const int y0 = 2 * my, x0 = 2 * mx0;  // x0 % 4 == 0 -> aligned float4
#pragma unroll
  for (int c = 0; c < COB; ++c) {
    float rA[4], rB[4];
#pragma unroll
    for (int q = 0; q < 4; ++q) {
      float a = accA[c][q], b = accB[c][q];
      if (ACT == 1) { a = fmaxf(a, 0.f); b = fmaxf(b, 0.f); }
      if (ACT == 2) {
        a = 1.f / (1.f + expf(-a));
        b = 1.f / (1.f + expf(-b));
      }
      rA[q] = a; rB[q] = b;
    }
    float* op = out + (((size_t)n * COUT + co0 + c) * HOUT + y0) * WOUT + x0;
    float4 lo; lo.x = rA[0]; lo.y = rA[1]; lo.z = rB[0]; lo.w = rB[1];
    float4 hi; hi.x = rA[2]; hi.y = rA[3]; hi.z = rB[2]; hi.w = rB[3];
    *reinterpret_cast<float4*>(op) = lo;
    *reinterpret_cast<float4*>(op + WOUT) = hi;
  }
}

// --------- numpy scalar pairwise row-sum of squares, n=256, fp32 -----------
__global__ __launch_bounds__(256) void z2_np_k(const float* __restrict__ z,
                                               float* __restrict__ z2) {
#pragma clang fp contract(off)
  const int p = blockIdx.x * 256 + threadIdx.x;  // 32768
  const int n = p >> 10, hw = p & 1023;
  const float* zb = z + (size_t)n * 262144 + hw;
  float blk[2];
#pragma unroll
  for (int b = 0; b < 2; ++b) {
    float r[8];
#pragma unroll
    for (int j = 0; j < 8; ++j) {
      const float v = zb[(size_t)(b * 128 + j) * 1024];
      r[j] = v * v;
    }
    for (int i = 8; i < 128; i += 8) {
#pragma unroll
      for (int j = 0; j < 8; ++j) {
        const float v = zb[(size_t)(b * 128 + i + j) * 1024];
        const float m = v * v;
        r[j] = r[j] + m;
      }
    }
    blk[b] = ((r[0] + r[1]) + (r[2] + r[3])) + ((r[4] + r[5]) + (r[6] + r[7]));
  }
  z2[p] = blk[0] + blk[1];
}

__global__ __launch_bounds__(256) void c2_np_k(const float* __restrict__ cb,
                                               float* __restrict__ c2) {
#pragma clang fp contract(off)
  const int jrow = blockIdx.x * 256 + threadIdx.x;  // 1024
  const float* row = cb + (size_t)jrow * 256;
  float blk[2];
#pragma unroll
  for (int b = 0; b < 2; ++b) {
    float r[8];
#pragma unroll
    for (int j = 0; j < 8; ++j) {
      const float v = row[b * 128 + j];
      r[j] = v * v;
    }
    for (int i = 8; i < 128; i += 8) {
#pragma unroll
      for (int j = 0; j < 8; ++j) {
        const float v = row[b * 128 + i + j];
        const float m = v * v;
        r[j] = r[j] + m;
      }
    }
    blk[b] = ((r[0] + r[1]) + (r[2] + r[3])) + ((r[4] + r[5]) + (r[6] + r[7]));
  }
  c2[jrow] = blk[0] + blk[1];
}

// ------ VQ scores: dist = fl(fl(z2 + c2) - 2*dot), chain dot, first-min ----
__global__ __launch_bounds__(256) void vq_scores_f32_k(
    const float* __restrict__ z, const float* __restrict__ cb,
    const float* __restrict__ z2, const float* __restrict__ c2,
    int* __restrict__ bestid) {
  __shared__ float zS[32][64];  // [dim-in-chunk][pixel]
  __shared__ float cS[64][33];  // [cw][dim-in-chunk]+pad
  const int tid = threadIdx.x;
  const int p0 = blockIdx.x * 64;  // 512 blocks
  const int n = p0 >> 10;
  const int hw0 = p0 & 1023;
  const float* zb = z + (size_t)n * 262144 + hw0;

  const int tp = tid >> 4;  // 0..15 : pixel group (4 pixels)
  const int tj = tid & 15;  // 0..15 : codeword lane

  float z2v[4];
#pragma unroll
  for (int ii = 0; ii < 4; ++ii) z2v[ii] = z2[p0 + tp * 4 + ii];

  float run_d[4];
  int run_id[4];
#pragma unroll
  for (int ii = 0; ii < 4; ++ii) { run_d[ii] = 3.4e38f; run_id[ii] = 0; }

  for (int j0 = 0; j0 < 1024; j0 += 64) {
    float acc[4][4];
#pragma unroll
    for (int a = 0; a < 4; ++a)
#pragma unroll
      for (int b = 0; b < 4; ++b) acc[a][b] = 0.f;

    for (int k0 = 0; k0 < 256; k0 += 32) {
      __syncthreads();
#pragma unroll
      for (int i = 0; i < 8; ++i) {
        const int q = i * 256 + tid;         // 0..2047
        const int zc = q >> 6, zl = q & 63;  // dim-in-chunk, pixel
        zS[zc][zl] = zb[(size_t)(k0 + zc) * 1024 + zl];
        const int cj = q >> 5, cd = q & 31;  // codeword, dim-in-chunk
        cS[cj][cd] = cb[(size_t)(j0 + cj) * 256 + k0 + cd];
      }
      __syncthreads();
#pragma unroll
      for (int d = 0; d < 32; ++d) {
        const float za = zS[d][tp * 4 + 0];
        const float zbv = zS[d][tp * 4 + 1];
        const float zc = zS[d][tp * 4 + 2];
        const float zd = zS[d][tp * 4 + 3];
        const float c0 = cS[0 * 16 + tj][d];
        const float c1 = cS[1 * 16 + tj][d];
        const float c2v = cS[2 * 16 + tj][d];
        const float c3 = cS[3 * 16 + tj][d];
        acc[0][0] = fmaf(za, c0, acc[0][0]);
        acc[0][1] = fmaf(za, c1, acc[0][1]);
        acc[0][2] = fmaf(za, c2v, acc[0][2]);
        acc[0][3] = fmaf(za, c3, acc[0][3]);
        acc[1][0] = fmaf(zbv, c0, acc[1][0]);
        acc[1][1] = fmaf(zbv, c1, acc[1][1]);
        acc[1][2] = fmaf(zbv, c2v, acc[1][2]);
        acc[1][3] = fmaf(zbv, c3, acc[1][3]);
        acc[2][0] = fmaf(zc, c0, acc[2][0]);
        acc[2][1] = fmaf(zc, c1, acc[2][1]);
        acc[2][2] = fmaf(zc, c2v, acc[2][2]);
        acc[2][3] = fmaf(zc, c3, acc[2][3]);
        acc[3][0] = fmaf(zd, c0, acc[3][0]);
        acc[3][1] = fmaf(zd, c1, acc[3][1]);
        acc[3][2] = fmaf(zd, c2v, acc[3][2]);
        acc[3][3] = fmaf(zd, c3, acc[3][3]);
      }
    }

    {
#pragma clang fp contract(off)
#pragma unroll
      for (int ii = 0; ii < 4; ++ii) {
#pragma unroll
        for (int jj = 0; jj < 4; ++jj) {
          const int j = j0 + jj * 16 + tj;
          const float m2 = 2.0f * acc[ii][jj];  // exact (power of 2)
          const float t1 = z2v[ii] + c2[j];     // fl(A + C)   <-- VQ-VAE idiom
          const float dist = t1 - m2;           // fl(T1 - B)
          if (dist < run_d[ii] || (dist == run_d[ii] && j < run_id[ii])) {
            run_d[ii] = dist;
            run_id[ii] = j;
          }
        }
      }
    }
  }

#pragma unroll
  for (int m = 1; m < 16; m <<= 1) {
#pragma unroll
    for (int ii = 0; ii < 4; ++ii) {
      const float od = __shfl_xor(run_d[ii], m, 64);
      const int oid = __shfl_xor(run_id[ii], m, 64);
      if (od < run_d[ii] || (od == run_d[ii] && oid < run_id[ii])) {
        run_d[ii] = od;
        run_id[ii] = oid;
      }
    }
  }
  if (tj == 0) {
#pragma unroll
    for (int ii = 0; ii < 4; ++ii) bestid[p0 + tp * 4 + ii] = run_id[ii];
  }
}

// ids / e_k from bestid (exact fp32 gather)
__global__ __launch_bounds__(256) void vq_gather_k(
    const int* __restrict__ bestid, const float* __restrict__ cb,
    float* __restrict__ ek, float* __restrict__ ids) {
  const int p = blockIdx.x * 256 + threadIdx.x;  // 32768
  const int id = bestid[p];
  ids[p] = (float)id;
  const int n = p >> 10, hw = p & 1023;
  float* ekb = ek + (size_t)n * 262144 + hw;
  const float* cbr = cb + (size_t)id * 256;
  for (int c = 0; c < 256; ++c) ekb[(size_t)c * 1024] = cbr[c];
}

// ---------------------------------------------------------------------------
extern "C" void kernel_launch(void* const* d_in, const int* in_sizes, int n_in,
                              void* d_out, int out_size, void* d_ws,
                              size_t ws_size, hipStream_t stream) {
  const float* x = (const float*)d_in[0];
  const float* enc_w0 = (const float*)d_in[1];
  const float* enc_w1 = (const float*)d_in[2];
  const float* enc_w2 = (const float*)d_in[3];
  const float* codebook = (const float*)d_in[4];
  const float* dec_w0 = (const float*)d_in[5];
  const float* dec_w1 = (const float*)d_in[6];
  const float* dec_w2 = (const float*)d_in[7];

  float* out = (float*)d_out;          // 6,291,456
  float* z_out = out + 6291456;        // 8,388,608
  float* ek_out = z_out + 8388608;     // 8,388,608
  float* ids_out = ek_out + 8388608;   // 32,768

  float* ws = (float*)d_ws;
  float* h1 = ws;                      // 33,554,432 f  (32,64,128,128)
  float* h2 = ws + 33554432;           // 16,777,216 f  (32,128,64,64)
  float* d1 = h2;                      // alias (h2 dead after conv3)
  float* d2 = h1;                      // alias (h1 dead after conv2)
  float* s = ws + 50331648;
  float* z2 = s;                       // 32,768 f
  float* c2 = s + 32768;               //  1,024 f
  int* bestid = (int*)(s + 33792);     // 32,768 i32

  // ---- encoder (fp32, PY=4 row-blocked; chains bit-identical) ----
  conv3x3_s2_py<3, 8, 4, 16, 1><<<dim3(16, 8, 32), 256, 0, stream>>>(
      x, enc_w0, h1, 64, 256, 256, 8);
  conv3x3_s2_py<64, 8, 4, 16, 1><<<dim3(4, 16, 32), 256, 0, stream>>>(
      h1, enc_w1, h2, 128, 128, 128, 4);
  conv3x3_s2_py<128, 8, 4, 32, 0><<<dim3(1, 32, 32), 256, 0, stream>>>(
      h2, enc_w2, z_out, 256, 64, 64, 1);

  // ---- VQ (fp32; dist = (z2 + c2) - 2dot) ----
  z2_np_k<<<128, 256, 0, stream>>>(z_out, z2);
  c2_np_k<<<4, 256, 0, stream>>>(codebook, c2);
  vq_scores_f32_k<<<512, 256, 0, stream>>>(z_out, codebook, z2, c2, bestid);
  vq_gather_k<<<128, 256, 0, stream>>>(bestid, codebook, ek_out, ids_out);

  // ---- decoder (fp32, parity-quad QX=2 deconv) ----
  deconv3x3_s2_quad2<256, 8, 1><<<dim3(2, 16, 32), 256, 0, stream>>>(
      ek_out, dec_w0, d1, 128, 32, 32, 1);
  deconv3x3_s2_quad2<128, 8, 1><<<dim3(8, 8, 32), 256, 0, stream>>>(
      d1, dec_w1, d2, 64, 64, 64, 2);
  deconv3x3_s2_quad2<64, 3, 2><<<dim3(32, 1, 32), 256, 0, stream>>>(
      d2, dec_w2, out, 3, 128, 128, 4);
}